// Round 5
// baseline (204.177 us; speedup 1.0000x reference)
//
#include <hip/hip_runtime.h>

// Conv2d + BN int8 quantized, MI355X gfx950. Inputs fp32, output fp32.
// R10: R9 hit 61us, limited by LDS port (8064 b64/CU ~38%) + 16x16 MFMA issue
// (41K cyc/CU). Switch to mfma_i32_32x32x32_i8, 64o x 64w per wave:
//   - MFMA instrs 4.13M -> 1.03M (pipe cyc/CU 41K -> ~15K, 4404 TOPS shape)
//   - B-fragment 16B/lane = 2x ds_read_b64 under the UNCHANGED 4-bit/8B qxp
//     swizzle (16-lane groups hit 16 distinct slots: conflict-free) ->
//     per-CU LDS reads halve.
//   - A/B layout: family pattern m=l&31, k=(l>>5)*16+e; C/D: verified
//     col=l&31, row=(r&3)+8*(r>>2)+4*(l>>5) (m74/m101, dtype-indep).
//   - quant_w repacked to per-lane A order; A dbuf one tap ahead.
//   - grid 1792 (block = 256o x 1 oh), chunked XCD swizzle 1792=8*224.
// Host falls back to the proven R5 fused kernel if ws_size is too small.

#define BATCH 32
#define CIN   128
#define HH    56
#define WW    56
#define OCH   256

typedef __attribute__((ext_vector_type(4))) int int4v;
typedef __attribute__((ext_vector_type(16))) int int16v;
typedef __attribute__((ext_vector_type(2))) long longx2;

#define QX_BYTES (32 * 56 * 56 * 128)           // 12,845,056  qxp[b][h][w][c]
#define QW_BYTES (256 * 1152)                   // 294,912 (fragment-packed)
#define WS_NEEDED (QX_BYTES + QW_BYTES + 1024)

__device__ __forceinline__ void gload_lds16(const void* g, void* l) {
  __builtin_amdgcn_global_load_lds(
      (const __attribute__((address_space(1))) unsigned int*)g,
      (__attribute__((address_space(3))) unsigned int*)l, 16, 0, 0);
}

// ---------------- kernel 1: weight quantization + fragment pack ------------
// One block per output channel o. A-fragment layout for 32x32x32 i8:
//   int4 index ((ot*9 + r)*4 + cs)*64 + lane  (ot = o>>5, r = kh*3+kw)
//   holds channels cs*32 + (lane>>5)*16 + 0..15 of row m = lane&31.
__global__ __launch_bounds__(256) void quant_w_kernel(
    const float* __restrict__ w, const float* __restrict__ sxp,
    char* __restrict__ qwf, float* __restrict__ alpha) {
  __shared__ float wf[1152];
  __shared__ float red[256];
  const int o = blockIdx.x;
  const int tid = threadIdx.x;
  const float* wrow = w + (size_t)o * 1152;
  float m = 0.f;
  for (int i = tid; i < 288; i += 256) {
    const float4 v = ((const float4*)wrow)[i];
    ((float4*)wf)[i] = v;
    m = fmaxf(m, fmaxf(fmaxf(fabsf(v.x), fabsf(v.y)),
                       fmaxf(fabsf(v.z), fabsf(v.w))));
  }
  red[tid] = m;
  __syncthreads();
  for (int s = 128; s > 0; s >>= 1) {
    if (tid < s) red[tid] = fmaxf(red[tid], red[tid + s]);
    __syncthreads();
  }
  const float sc = red[0] / 127.0f;   // max/QMAX, fp32, matches reference
  if (tid == 0) alpha[o] = sc * sxp[0];
  if (tid < 72) {   // r = tid/8, cs = (tid>>1)&3, hi = tid&1 : one 16B each
    const int r = tid >> 3, cs = (tid >> 1) & 3, hi = tid & 1;
    const int ot = o >> 5, ml = o & 31;
    int4v pk;
#pragma unroll
    for (int d = 0; d < 4; ++d) {
      unsigned int p = 0;
#pragma unroll
      for (int k = 0; k < 4; ++k) {
        const int c = cs * 32 + hi * 16 + d * 4 + k;
        const int q =
            (int)fminf(127.f, fmaxf(-127.f, rintf(wf[c * 9 + r] / sc)));
        p |= ((unsigned int)(q & 255)) << (8 * k);
      }
      pk[d] = (int)p;
    }
    *(int4v*)(qwf +
              ((((size_t)ot * 9 + r) * 4 + cs) * 64 + ml + 32 * hi) * 16) = pk;
  }
}

// ---------------- kernel 2: x quantization -> swizzled im2col rows ---------
// qxp byte ((b*56+h)*56 + w)*128 + j holds q(x[b][ j^(((w+1)&15)<<3) ][h][w]).
__global__ __launch_bounds__(256) void quant_x_kernel(
    const float* __restrict__ x, const float* __restrict__ sxp,
    unsigned int* __restrict__ qxp) {
  __shared__ char ldsA[128 * 60];   // [c][w] quantized bytes, stride 60
  const int row = blockIdx.x;       // b*56 + h
  const int b = row / 56, h = row % 56;
  const float sx = sxp[0];
  for (int i = threadIdx.x; i < 1792; i += 256) {
    const int c = i / 14, f = i % 14;
    const float4 v =
        *(const float4*)(x + (((size_t)b * 128 + c) * 56 + h) * 56 + 4 * f);
    unsigned int pk;
    pk  = (unsigned int)((int)fminf(127.f, fmaxf(-127.f, rintf(v.x / sx))) & 255);
    pk |= ((unsigned int)((int)fminf(127.f, fmaxf(-127.f, rintf(v.y / sx))) & 255)) << 8;
    pk |= ((unsigned int)((int)fminf(127.f, fmaxf(-127.f, rintf(v.z / sx))) & 255)) << 16;
    pk |= ((unsigned int)((int)fminf(127.f, fmaxf(-127.f, rintf(v.w / sx))) & 255)) << 24;
    *(unsigned int*)(ldsA + c * 60 + 4 * f) = pk;
  }
  __syncthreads();
  unsigned int* orow = qxp + (size_t)row * 56 * 32;
  for (int i = threadIdx.x; i < 1792; i += 256) {
    const int w = i >> 5, jd = i & 31;
    // byte p of row w holds channel p ^ (((w+1)&15)<<3); dword-level: ph<<1
    const int c0 = (jd ^ (((w + 1) & 15) << 1)) << 2;  // channel base (4-run)
    unsigned int pk = 0;
#pragma unroll
    for (int k = 0; k < 4; ++k)
      pk |= ((unsigned int)(unsigned char)ldsA[(c0 + k) * 60 + w]) << (8 * k);
    orow[i] = pk;
  }
}

// ---------------- kernel 3: conv (32x32x32 i8 MFMA, weights from L2) -------
#define XSLAB 8448                  // 66 cols * 128B, contiguous (no pad)

__global__ __launch_bounds__(256, 3) void conv_kernel(
    const char* __restrict__ qxp, const char* __restrict__ qwf,
    const float* __restrict__ alpha, const float* __restrict__ bias,
    float* __restrict__ out) {
  __shared__ __attribute__((aligned(16))) char Xs8[3 * XSLAB];  // 25,344 B

  // chunked XCD swizzle: 1792 = 8*224; XCD (id&7) owns bi in [xcd*224,+224)
  const int id = blockIdx.x;
  const int xcd = id & 7;
  const int bi = xcd * 224 + (id >> 3);
  const int b  = bi / 56;
  const int oh = bi % 56;
  const int tid = threadIdx.x;
  const int wave = tid >> 6, lane = tid & 63;
  const int l31 = lane & 31, hi = lane >> 5;

  // ---- stage 3 input rows: contiguous async copies + small zero fills ----
  for (int kh = 0; kh < 3; ++kh) {
    const int ih = oh - 1 + kh;
    char* slab = Xs8 + kh * XSLAB;
    if (ih >= 0 && ih < HH) {
      const char* src = qxp + ((size_t)b * 56 + ih) * 7168;
      for (int i = tid; i < 448; i += 256)
        gload_lds16(src + i * 16, slab + 128 + i * 16);   // cols 1..56
      for (int i = tid; i < 320; i += 256) {              // zero cols 0,57..65
        const int cg = i >> 5, dw = i & 31;
        const int col = (cg == 0) ? 0 : 56 + cg;
        ((unsigned int*)slab)[col * 32 + dw] = 0u;
      }
    } else {
      for (int i = tid; i < 2112; i += 256) ((unsigned int*)slab)[i] = 0u;
    }
  }

  // A-operand: per-lane int4 (16B), fragment-packed; wave chunk = 1KB/load.
  const int4v* wb = (const int4v*)qwf;
  const int ot0 = wave * 2;         // wave covers o in [wave*64, wave*64+64)
  int4v ap[2][2][4];                // [buf][ot][cs]
#pragma unroll
  for (int ot = 0; ot < 2; ++ot)
#pragma unroll
    for (int cs = 0; cs < 4; ++cs)
      ap[0][ot][cs] = wb[(((size_t)(ot0 + ot) * 9 + 0) * 4 + cs) * 64 + lane];

  int16v acc[2][2];
#pragma unroll
  for (int ot = 0; ot < 2; ++ot)
#pragma unroll
    for (int u = 0; u < 2; ++u)
#pragma unroll
      for (int r = 0; r < 16; ++r) acc[ot][u][r] = 0;

  __syncthreads();   // drains vmcnt (global_load_lds + ap[0]) + lgkm

  // 9 taps, A double-buffered one tap ahead (all indices static).
#pragma unroll
  for (int g = 0; g < 9; ++g) {
    const int kh = g / 3, kw = g % 3;
    if (g < 8) {
#pragma unroll
      for (int ot = 0; ot < 2; ++ot)
#pragma unroll
        for (int cs = 0; cs < 4; ++cs)
          ap[(g + 1) & 1][ot][cs] =
              wb[(((size_t)(ot0 + ot) * 9 + (g + 1)) * 4 + cs) * 64 + lane];
    }
    const char* Xk = Xs8 + kh * XSLAB;
    const int ph = ((l31 + kw) & 15) << 3;  // col&15 phase, u-invariant
#pragma unroll
    for (int cs = 0; cs < 4; ++cs) {
      int4v bop[2];
#pragma unroll
      for (int u = 0; u < 2; ++u) {
        const int col = u * 32 + l31 + kw;
        const int base = (cs * 32 + hi * 16) ^ ph;
        longx2 q;
        q[0] = *(const long*)(Xk + col * 128 + base);        // k bytes 0..7
        q[1] = *(const long*)(Xk + col * 128 + (base ^ 8));  // k bytes 8..15
        bop[u] = __builtin_bit_cast(int4v, q);
      }
#pragma unroll
      for (int ot = 0; ot < 2; ++ot)
#pragma unroll
        for (int u = 0; u < 2; ++u)
          acc[ot][u] = __builtin_amdgcn_mfma_i32_32x32x32_i8(
              ap[g & 1][ot][cs], bop[u], acc[ot][u], 0, 0, 0);
    }
  }

  // C/D layout (HW-verified m74/m101, dtype-independent):
  //   col = lane&31, row = (r&3) + 8*(r>>2) + 4*(lane>>5)
#pragma unroll
  for (int ot = 0; ot < 2; ++ot) {
    const int obase = wave * 64 + ot * 32;
#pragma unroll
    for (int r = 0; r < 16; ++r) {
      const int o = obase + (r & 3) + 8 * (r >> 2) + 4 * hi;
      const float al = alpha[o], bz = bias[o];
#pragma unroll
      for (int u = 0; u < 2; ++u) {
        const int ow = u * 32 + l31;
        if (ow < WW)
          out[(((size_t)b * OCH + o) * HH + oh) * WW + ow] =
              (float)acc[ot][u][r] * al + bz;
      }
    }
  }
}

// ---------------- fallback: R5's proven fused kernel (ws-free) -------------
#define FAS_ROW 392
#define FXS_ROW 136
#define FLDS_XS (128 * FAS_ROW)
#define FLDS_SC (FLDS_XS + 66 * FXS_ROW)
#define FLDS_AL (FLDS_SC + 512)
#define FLDS_BI (FLDS_AL + 512)
#define FLDS_RED (FLDS_BI + 512)
#define FLDS_TOT (FLDS_RED + 1024)

__global__ __launch_bounds__(256) void conv_fused_kernel(
    const float* __restrict__ x, const float* __restrict__ w,
    const float* __restrict__ bias, const float* __restrict__ sxp,
    float* __restrict__ out) {
  __shared__ __attribute__((aligned(16))) char lds[FLDS_TOT];
  char* As8 = lds;
  char* Xs8 = lds + FLDS_XS;
  float* scaleS = (float*)(lds + FLDS_SC);
  float* alphaS = (float*)(lds + FLDS_AL);
  float* biasS  = (float*)(lds + FLDS_BI);
  float* red    = (float*)(lds + FLDS_RED);

  const int bi = blockIdx.x;
  const int b  = bi / 56;
  const int oh = bi % 56;
  const int o0 = blockIdx.y * 128;
  const int tid = threadIdx.x;
  const int wave = tid >> 6, lane = tid & 63;
  const int l16 = lane & 15, quad = lane >> 4;
  const float sx = sxp[0];

  int m_r[4], n_r[4];
  {
    int4v zz = {0, 0, 0, 0};
    long a1 = 0, b1 = 0, a2 = 0, b2 = 0;
    if (quad == 0) { a1 = 1L; b1 = (long)(l16 + 1); a2 = (long)(l16 + 1); b2 = 1L; }
    int4v d1 = __builtin_amdgcn_mfma_i32_16x16x32_i8(a1, b1, zz, 0, 0, 0);
    int4v d2 = __builtin_amdgcn_mfma_i32_16x16x32_i8(a2, b2, zz, 0, 0, 0);
#pragma unroll
    for (int r = 0; r < 4; ++r) { n_r[r] = (d1[r] - 1) & 15; m_r[r] = (d2[r] - 1) & 15; }
  }
  {
    const int o = tid >> 1, half = tid & 1;
    const float4* p = (const float4*)(w + (size_t)(o0 + o) * 1152 + half * 576);
    float m = 0.f;
#pragma unroll 4
    for (int i = 0; i < 144; ++i) {
      const float4 v = p[i];
      m = fmaxf(m, fmaxf(fmaxf(fabsf(v.x), fabsf(v.y)), fmaxf(fabsf(v.z), fabsf(v.w))));
    }
    red[tid] = m;
  }
  __syncthreads();
  {
    const int o = tid >> 1;
    if ((tid & 1) == 0) {
      const float sc = fmaxf(red[2 * o], red[2 * o + 1]) / 127.0f;
      scaleS[o] = sc; alphaS[o] = sc * sx; biasS[o] = bias[o0 + o];
    }
  }
  int4v acc[2][4];
#pragma unroll
  for (int t = 0; t < 2; ++t)
#pragma unroll
    for (int u = 0; u < 4; ++u) acc[t][u] = (int4v){0, 0, 0, 0};

  for (int kh = 0; kh < 3; ++kh) {
    const int ih = oh - 1 + kh;
    const bool row_ok = (ih >= 0) && (ih < HH);
    __syncthreads();
    for (int idx = tid; idx < 66 * 128; idx += 256) {
      const int col = idx % 66, c = idx / 66, iw = col - 1;
      int q = 0;
      if (row_ok && iw >= 0 && iw < WW) {
        const float xv = x[(((size_t)b * CIN + c) * HH + ih) * WW + iw];
        q = (int)fminf(127.f, fmaxf(-127.f, rintf(xv / sx)));
      }
      Xs8[col * FXS_ROW + c] = (char)q;
    }
    for (int idx = tid; idx < 16384; idx += 256) {
      const int c = idx & 127, o = idx >> 7;
      const float s = scaleS[o];
      const float* wp = w + (size_t)(o0 + o) * 1152 + c * 9 + kh * 3;
#pragma unroll
      for (int kw = 0; kw < 3; ++kw) {
        const int q = (int)fminf(127.f, fmaxf(-127.f, rintf(wp[kw] / s)));
        As8[o * FAS_ROW + kw * 128 + c] = (char)q;
      }
    }
    __syncthreads();
    const int obase = wave * 32;
#pragma unroll
    for (int kw = 0; kw < 3; ++kw) {
#pragma unroll
      for (int c0 = 0; c0 < 128; c0 += 32) {
        long aop[2], bop[4];
#pragma unroll
        for (int t = 0; t < 2; ++t)
          aop[t] = *(const long*)(As8 + (obase + t * 16 + l16) * FAS_ROW + kw * 128 + c0 + quad * 8);
#pragma unroll
        for (int u = 0; u < 4; ++u)
          bop[u] = *(const long*)(Xs8 + (u * 16 + l16 + kw) * FXS_ROW + c0 + quad * 8);
#pragma unroll
        for (int t = 0; t < 2; ++t)
#pragma unroll
          for (int u = 0; u < 4; ++u)
            acc[t][u] = __builtin_amdgcn_mfma_i32_16x16x32_i8(aop[t], bop[u], acc[t][u], 0, 0, 0);
      }
    }
  }
#pragma unroll
  for (int t = 0; t < 2; ++t) {
#pragma unroll
    for (int u = 0; u < 4; ++u) {
#pragma unroll
      for (int r = 0; r < 4; ++r) {
        const int ol = wave * 32 + t * 16 + m_r[r];
        const int ow = u * 16 + n_r[r];
        if (ow < WW)
          out[(((size_t)b * OCH + o0 + ol) * HH + oh) * WW + ow] =
              (float)acc[t][u][r] * alphaS[ol] + biasS[ol];
      }
    }
  }
}

extern "C" void kernel_launch(void* const* d_in, const int* in_sizes, int n_in,
                              void* d_out, int out_size, void* d_ws, size_t ws_size,
                              hipStream_t stream) {
  const float *x = nullptr, *w = nullptr, *bias = nullptr, *sx = nullptr;
  for (int i = 0; i < n_in; ++i) {
    const int s = in_sizes[i];
    if (s == BATCH * CIN * HH * WW) x = (const float*)d_in[i];
    else if (s == OCH * CIN * 9)    w = (const float*)d_in[i];
    else if (s == OCH)              bias = (const float*)d_in[i];
    else if (s == 1)                sx = (const float*)d_in[i];
  }
  if (!x || !w || !bias || !sx) {
    x = (const float*)d_in[0]; w = (const float*)d_in[1];
    bias = (const float*)d_in[2]; sx = (const float*)d_in[3];
  }
  float* out = (float*)d_out;

  if (ws_size >= (size_t)WS_NEEDED) {
    unsigned int* qxp = (unsigned int*)d_ws;
    char* qwf = (char*)d_ws + QX_BYTES;
    float* alpha = (float*)((char*)d_ws + QX_BYTES + QW_BYTES);
    quant_w_kernel<<<OCH, 256, 0, stream>>>(w, sx, qwf, alpha);
    quant_x_kernel<<<BATCH * HH, 256, 0, stream>>>(x, sx, qxp);
    conv_kernel<<<BATCH * HH, 256, 0, stream>>>(
        (const char*)qxp, qwf, alpha, bias, out);
  } else {
    conv_fused_kernel<<<dim3(BATCH * HH, 2), 256, 0, stream>>>(x, w, bias, sx, out);
  }
}

// Round 6
// 191.044 us; speedup vs baseline: 1.0687x; 1.0687x over previous
//
#include <hip/hip_runtime.h>

// Conv2d + BN int8 quantized, MI355X gfx950. Inputs fp32, output fp32.
// R11: R10 (32x32 MFMA, 64o/wave) regressed 61->70us: acc=64 AGPR + 68 VGPR
// halved occupancy (50->24%) -- the accumulator wall. o/wave=32 is the sweet
// spot. Revert to R9's proven 16x16x32 structure (61us) and attack its real
// limit: just-in-time ds_reads (VGPR cap 85 at bounds(256,6) left no room).
//   - launch_bounds(256,4): 128-reg cap (occupancy measured 4 blk/CU anyway).
//   - explicit B ping-pong: each of 36 unrolled (g,c04) steps prefetches the
//     next step's 4 ds_read_b64 before its 8 MFMAs (static indices only).
//   - A dbuf one tap ahead as in R9; single barrier per block.
// Host falls back to the proven R5 fused kernel if ws_size is too small.

#define BATCH 32
#define CIN   128
#define HH    56
#define WW    56
#define OCH   256

typedef __attribute__((ext_vector_type(4))) int int4v;
typedef __attribute__((ext_vector_type(2))) long longx2;

#define QX_BYTES (32 * 56 * 56 * 128)           // 12,845,056  qxp[b][h][w][c]
#define QW_BYTES (256 * 1152)                   // 294,912 (fragment-packed)
#define WS_NEEDED (QX_BYTES + QW_BYTES + 1024)

__device__ __forceinline__ void gload_lds16(const void* g, void* l) {
  __builtin_amdgcn_global_load_lds(
      (const __attribute__((address_space(1))) unsigned int*)g,
      (__attribute__((address_space(3))) unsigned int*)l, 16, 0, 0);
}

// ---------------- kernel 1: weight quantization + fragment pack ------------
// One block per output channel o. Layout (t-pair merged into long2):
//   byte ((og*36 + r*4 + c04)*128 + (l16*4+quad)*2 + t)*8 + (half*4+k)
//   holds channel c04*32+quad*8+half*4+k of o = og*32+t*16+l16 at tap r.
// Conv lane (l16,quad) loads long2 at longx2 index (r*4+c04)*64 + l16*4+quad:
//   [0] = t=0 operand, [1] = t=1 operand; wave chunk = contiguous 1KB.
__global__ __launch_bounds__(256) void quant_w_kernel(
    const float* __restrict__ w, const float* __restrict__ sxp,
    char* __restrict__ qwf, float* __restrict__ alpha) {
  __shared__ float wf[1152];
  __shared__ float red[256];
  const int o = blockIdx.x;
  const int tid = threadIdx.x;
  const float* wrow = w + (size_t)o * 1152;
  float m = 0.f;
  for (int i = tid; i < 288; i += 256) {
    const float4 v = ((const float4*)wrow)[i];
    ((float4*)wf)[i] = v;
    m = fmaxf(m, fmaxf(fmaxf(fabsf(v.x), fabsf(v.y)),
                       fmaxf(fabsf(v.z), fabsf(v.w))));
  }
  red[tid] = m;
  __syncthreads();
  for (int s = 128; s > 0; s >>= 1) {
    if (tid < s) red[tid] = fmaxf(red[tid], red[tid + s]);
    __syncthreads();
  }
  const float sc = red[0] / 127.0f;   // max/QMAX, fp32, matches reference
  if (tid == 0) alpha[o] = sc * sxp[0];
  if (tid < 36) {
    const int r = tid >> 2, c04 = tid & 3;
    const int og = o >> 5, t = (o >> 4) & 1, l16 = o & 15;
    unsigned int* base = (unsigned int*)(qwf + (size_t)og * 36864 +
                                         (size_t)(r * 4 + c04) * 1024);
#pragma unroll
    for (int quad = 0; quad < 4; ++quad) {
#pragma unroll
      for (int half = 0; half < 2; ++half) {
        unsigned int pk = 0;
#pragma unroll
        for (int k = 0; k < 4; ++k) {
          const int c = c04 * 32 + quad * 8 + half * 4 + k;
          const int q =
              (int)fminf(127.f, fmaxf(-127.f, rintf(wf[c * 9 + r] / sc)));
          pk |= ((unsigned int)(q & 255)) << (8 * k);
        }
        base[(l16 * 4 + quad) * 4 + t * 2 + half] = pk;
      }
    }
  }
}

// ---------------- kernel 2: x quantization -> swizzled im2col rows ---------
// qxp byte ((b*56+h)*56 + w)*128 + j holds q(x[b][ j^(((w+1)&15)<<3) ][h][w]).
__global__ __launch_bounds__(256) void quant_x_kernel(
    const float* __restrict__ x, const float* __restrict__ sxp,
    unsigned int* __restrict__ qxp) {
  __shared__ char ldsA[128 * 60];   // [c][w] quantized bytes, stride 60
  const int row = blockIdx.x;       // b*56 + h
  const int b = row / 56, h = row % 56;
  const float sx = sxp[0];
  for (int i = threadIdx.x; i < 1792; i += 256) {
    const int c = i / 14, f = i % 14;
    const float4 v =
        *(const float4*)(x + (((size_t)b * 128 + c) * 56 + h) * 56 + 4 * f);
    unsigned int pk;
    pk  = (unsigned int)((int)fminf(127.f, fmaxf(-127.f, rintf(v.x / sx))) & 255);
    pk |= ((unsigned int)((int)fminf(127.f, fmaxf(-127.f, rintf(v.y / sx))) & 255)) << 8;
    pk |= ((unsigned int)((int)fminf(127.f, fmaxf(-127.f, rintf(v.z / sx))) & 255)) << 16;
    pk |= ((unsigned int)((int)fminf(127.f, fmaxf(-127.f, rintf(v.w / sx))) & 255)) << 24;
    *(unsigned int*)(ldsA + c * 60 + 4 * f) = pk;
  }
  __syncthreads();
  unsigned int* orow = qxp + (size_t)row * 56 * 32;
  for (int i = threadIdx.x; i < 1792; i += 256) {
    const int w = i >> 5, jd = i & 31;
    // byte p of row w holds channel p ^ (((w+1)&15)<<3); dword-level: ph<<1
    const int c0 = (jd ^ (((w + 1) & 15) << 1)) << 2;  // channel base (4-run)
    unsigned int pk = 0;
#pragma unroll
    for (int k = 0; k < 4; ++k)
      pk |= ((unsigned int)(unsigned char)ldsA[(c0 + k) * 60 + w]) << (8 * k);
    orow[i] = pk;
  }
}

// ---------------- kernel 3: conv (i8 MFMA, weights from L2) ----------------
#define XSLAB 8448                  // 66 cols * 128B, contiguous (no pad)

__global__ __launch_bounds__(256, 4) void conv_kernel(
    const char* __restrict__ qxp, const char* __restrict__ qwf,
    const float* __restrict__ alpha, const float* __restrict__ bias,
    float* __restrict__ out) {
  __shared__ __attribute__((aligned(16))) char Xs8[3 * XSLAB];  // 25,344 B

  // chunked XCD swizzle: XCD (id&7) owns bi in [xcd*224, xcd*224+224), both y
  const int id = blockIdx.x;        // 0..3583, grid is 1-D
  const int xcd = id & 7;
  int kk = id >> 3;                 // 0..447
  const int yy = (kk >= 224) ? 1 : 0;
  kk -= yy * 224;                   // 0..223
  const int bi = xcd * 224 + kk;
  const int b  = bi / 56;
  const int oh = bi % 56;
  const int o0 = yy * 128;
  const int tid = threadIdx.x;
  const int wave = tid >> 6, lane = tid & 63;
  const int l16 = lane & 15, quad = lane >> 4;

  // in-block MFMA C/D layout probe (verified working since R5)
  int m_r[4], n_r[4];
  {
    int4v zz = {0, 0, 0, 0};
    long a1 = 0, b1 = 0, a2 = 0, b2 = 0;
    if (quad == 0) {
      a1 = 1L;               // A = delta(k=0)
      b1 = (long)(l16 + 1);  // B[0][n] = n+1
      a2 = (long)(l16 + 1);  // A[m][0] = m+1
      b2 = 1L;               // B = delta(k=0)
    }
    int4v d1 = __builtin_amdgcn_mfma_i32_16x16x32_i8(a1, b1, zz, 0, 0, 0);
    int4v d2 = __builtin_amdgcn_mfma_i32_16x16x32_i8(a2, b2, zz, 0, 0, 0);
#pragma unroll
    for (int r = 0; r < 4; ++r) {
      n_r[r] = (d1[r] - 1) & 15;
      m_r[r] = (d2[r] - 1) & 15;
    }
  }

  // A-operand base: per-lane long2 (t=0,t=1 fragments), wave chunk = 1KB.
  const longx2* wb2 = (const longx2*)(qwf + (size_t)(yy * 4 + wave) * 36864) +
                      (l16 * 4 + quad);
  longx2 ap[2][4];
#pragma unroll
  for (int c04 = 0; c04 < 4; ++c04) ap[0][c04] = wb2[(size_t)c04 * 64];

  // ---- stage 3 input rows: contiguous async copies + small zero fills ----
  for (int kh = 0; kh < 3; ++kh) {
    const int ih = oh - 1 + kh;
    char* slab = Xs8 + kh * XSLAB;
    if (ih >= 0 && ih < HH) {
      const char* src = qxp + ((size_t)b * 56 + ih) * 7168;
      for (int i = tid; i < 448; i += 256)
        gload_lds16(src + i * 16, slab + 128 + i * 16);   // cols 1..56
      for (int i = tid; i < 320; i += 256) {              // zero cols 0,57..65
        const int cg = i >> 5, dw = i & 31;
        const int col = (cg == 0) ? 0 : 56 + cg;
        ((unsigned int*)slab)[col * 32 + dw] = 0u;
      }
    } else {
      for (int i = tid; i < 2112; i += 256) ((unsigned int*)slab)[i] = 0u;
    }
  }

  int4v acc[2][4];
#pragma unroll
  for (int t = 0; t < 2; ++t)
#pragma unroll
    for (int u = 0; u < 4; ++u) acc[t][u] = (int4v){0, 0, 0, 0};

  __syncthreads();   // drains vmcnt (global_load_lds + ap[0]) + lgkm

  // ---- K-loop: 36 steps (9 taps x 4 c04), B ping-ponged one step ahead ----
  long bops[2][4];
  {
    const int ph0 = (l16 & 15) << 3;        // g=0: kh=0, kw=0
    const int boff0 = (quad * 8) ^ ph0;     // c04=0
#pragma unroll
    for (int u = 0; u < 4; ++u)
      bops[0][u] = *(const long*)(Xs8 + (u * 16 + l16) * 128 + boff0);
  }
#pragma unroll
  for (int step = 0; step < 36; ++step) {
    const int g = step >> 2, c04 = step & 3;
    // prefetch next step's B fragments (static after unroll)
    if (step + 1 < 36) {
      const int gn = (step + 1) >> 2, cn = (step + 1) & 3;
      const int khn = gn / 3, kwn = gn % 3;
      const char* Xkn = Xs8 + khn * XSLAB;
      const int phn = ((l16 + kwn) & 15) << 3;
      const int boffn = (cn * 32 + quad * 8) ^ phn;
#pragma unroll
      for (int u = 0; u < 4; ++u)
        bops[(step + 1) & 1][u] =
            *(const long*)(Xkn + (u * 16 + l16 + kwn) * 128 + boffn);
    }
    // prefetch next tap's A fragments (once per g)
    if (c04 == 0 && g < 8) {
#pragma unroll
      for (int cc = 0; cc < 4; ++cc)
        ap[(g + 1) & 1][cc] = wb2[(size_t)((g + 1) * 4 + cc) * 64];
    }
#pragma unroll
    for (int u = 0; u < 4; ++u) {
      acc[0][u] = __builtin_amdgcn_mfma_i32_16x16x32_i8(
          ap[g & 1][c04][0], bops[step & 1][u], acc[0][u], 0, 0, 0);
      acc[1][u] = __builtin_amdgcn_mfma_i32_16x16x32_i8(
          ap[g & 1][c04][1], bops[step & 1][u], acc[1][u], 0, 0, 0);
    }
  }

#pragma unroll
  for (int t = 0; t < 2; ++t) {
#pragma unroll
    for (int u = 0; u < 4; ++u) {
#pragma unroll
      for (int r = 0; r < 4; ++r) {
        const int ol = wave * 32 + t * 16 + m_r[r];
        const int ow = u * 16 + n_r[r];
        if (ow < WW) {
          const int oo = o0 + ol;
          out[(((size_t)b * OCH + oo) * HH + oh) * WW + ow] =
              (float)acc[t][u][r] * alpha[oo] + bias[oo];
        }
      }
    }
  }
}

// ---------------- fallback: R5's proven fused kernel (ws-free) -------------
#define FAS_ROW 392
#define FXS_ROW 136
#define FLDS_XS (128 * FAS_ROW)
#define FLDS_SC (FLDS_XS + 66 * FXS_ROW)
#define FLDS_AL (FLDS_SC + 512)
#define FLDS_BI (FLDS_AL + 512)
#define FLDS_RED (FLDS_BI + 512)
#define FLDS_TOT (FLDS_RED + 1024)

__global__ __launch_bounds__(256) void conv_fused_kernel(
    const float* __restrict__ x, const float* __restrict__ w,
    const float* __restrict__ bias, const float* __restrict__ sxp,
    float* __restrict__ out) {
  __shared__ __attribute__((aligned(16))) char lds[FLDS_TOT];
  char* As8 = lds;
  char* Xs8 = lds + FLDS_XS;
  float* scaleS = (float*)(lds + FLDS_SC);
  float* alphaS = (float*)(lds + FLDS_AL);
  float* biasS  = (float*)(lds + FLDS_BI);
  float* red    = (float*)(lds + FLDS_RED);

  const int bi = blockIdx.x;
  const int b  = bi / 56;
  const int oh = bi % 56;
  const int o0 = blockIdx.y * 128;
  const int tid = threadIdx.x;
  const int wave = tid >> 6, lane = tid & 63;
  const int l16 = lane & 15, quad = lane >> 4;
  const float sx = sxp[0];

  int m_r[4], n_r[4];
  {
    int4v zz = {0, 0, 0, 0};
    long a1 = 0, b1 = 0, a2 = 0, b2 = 0;
    if (quad == 0) { a1 = 1L; b1 = (long)(l16 + 1); a2 = (long)(l16 + 1); b2 = 1L; }
    int4v d1 = __builtin_amdgcn_mfma_i32_16x16x32_i8(a1, b1, zz, 0, 0, 0);
    int4v d2 = __builtin_amdgcn_mfma_i32_16x16x32_i8(a2, b2, zz, 0, 0, 0);
#pragma unroll
    for (int r = 0; r < 4; ++r) { n_r[r] = (d1[r] - 1) & 15; m_r[r] = (d2[r] - 1) & 15; }
  }
  {
    const int o = tid >> 1, half = tid & 1;
    const float4* p = (const float4*)(w + (size_t)(o0 + o) * 1152 + half * 576);
    float m = 0.f;
#pragma unroll 4
    for (int i = 0; i < 144; ++i) {
      const float4 v = p[i];
      m = fmaxf(m, fmaxf(fmaxf(fabsf(v.x), fabsf(v.y)), fmaxf(fabsf(v.z), fabsf(v.w))));
    }
    red[tid] = m;
  }
  __syncthreads();
  {
    const int o = tid >> 1;
    if ((tid & 1) == 0) {
      const float sc = fmaxf(red[2 * o], red[2 * o + 1]) / 127.0f;
      scaleS[o] = sc; alphaS[o] = sc * sx; biasS[o] = bias[o0 + o];
    }
  }
  int4v acc[2][4];
#pragma unroll
  for (int t = 0; t < 2; ++t)
#pragma unroll
    for (int u = 0; u < 4; ++u) acc[t][u] = (int4v){0, 0, 0, 0};

  for (int kh = 0; kh < 3; ++kh) {
    const int ih = oh - 1 + kh;
    const bool row_ok = (ih >= 0) && (ih < HH);
    __syncthreads();
    for (int idx = tid; idx < 66 * 128; idx += 256) {
      const int col = idx % 66, c = idx / 66, iw = col - 1;
      int q = 0;
      if (row_ok && iw >= 0 && iw < WW) {
        const float xv = x[(((size_t)b * CIN + c) * HH + ih) * WW + iw];
        q = (int)fminf(127.f, fmaxf(-127.f, rintf(xv / sx)));
      }
      Xs8[col * FXS_ROW + c] = (char)q;
    }
    for (int idx = tid; idx < 16384; idx += 256) {
      const int c = idx & 127, o = idx >> 7;
      const float s = scaleS[o];
      const float* wp = w + (size_t)(o0 + o) * 1152 + c * 9 + kh * 3;
#pragma unroll
      for (int kw = 0; kw < 3; ++kw) {
        const int q = (int)fminf(127.f, fmaxf(-127.f, rintf(wp[kw] / s)));
        As8[o * FAS_ROW + kw * 128 + c] = (char)q;
      }
    }
    __syncthreads();
    const int obase = wave * 32;
#pragma unroll
    for (int kw = 0; kw < 3; ++kw) {
#pragma unroll
      for (int c0 = 0; c0 < 128; c0 += 32) {
        long aop[2], bop[4];
#pragma unroll
        for (int t = 0; t < 2; ++t)
          aop[t] = *(const long*)(As8 + (obase + t * 16 + l16) * FAS_ROW + kw * 128 + c0 + quad * 8);
#pragma unroll
        for (int u = 0; u < 4; ++u)
          bop[u] = *(const long*)(Xs8 + (u * 16 + l16 + kw) * FXS_ROW + c0 + quad * 8);
#pragma unroll
        for (int t = 0; t < 2; ++t)
#pragma unroll
          for (int u = 0; u < 4; ++u)
            acc[t][u] = __builtin_amdgcn_mfma_i32_16x16x32_i8(aop[t], bop[u], acc[t][u], 0, 0, 0);
      }
    }
  }
#pragma unroll
  for (int t = 0; t < 2; ++t) {
#pragma unroll
    for (int u = 0; u < 4; ++u) {
#pragma unroll
      for (int r = 0; r < 4; ++r) {
        const int ol = wave * 32 + t * 16 + m_r[r];
        const int ow = u * 16 + n_r[r];
        if (ow < WW)
          out[(((size_t)b * OCH + o0 + ol) * HH + oh) * WW + ow] =
              (float)acc[t][u][r] * alphaS[ol] + biasS[ol];
      }
    }
  }
}

extern "C" void kernel_launch(void* const* d_in, const int* in_sizes, int n_in,
                              void* d_out, int out_size, void* d_ws, size_t ws_size,
                              hipStream_t stream) {
  const float *x = nullptr, *w = nullptr, *bias = nullptr, *sx = nullptr;
  for (int i = 0; i < n_in; ++i) {
    const int s = in_sizes[i];
    if (s == BATCH * CIN * HH * WW) x = (const float*)d_in[i];
    else if (s == OCH * CIN * 9)    w = (const float*)d_in[i];
    else if (s == OCH)              bias = (const float*)d_in[i];
    else if (s == 1)                sx = (const float*)d_in[i];
  }
  if (!x || !w || !bias || !sx) {
    x = (const float*)d_in[0]; w = (const float*)d_in[1];
    bias = (const float*)d_in[2]; sx = (const float*)d_in[3];
  }
  float* out = (float*)d_out;

  if (ws_size >= (size_t)WS_NEEDED) {
    unsigned int* qxp = (unsigned int*)d_ws;
    char* qwf = (char*)d_ws + QX_BYTES;
    float* alpha = (float*)((char*)d_ws + QX_BYTES + QW_BYTES);
    quant_w_kernel<<<OCH, 256, 0, stream>>>(w, sx, qwf, alpha);
    quant_x_kernel<<<BATCH * HH, 256, 0, stream>>>(x, sx, qxp);
    conv_kernel<<<BATCH * HH * 2, 256, 0, stream>>>(
        (const char*)qxp, qwf, alpha, bias, out);
  } else {
    conv_fused_kernel<<<dim3(BATCH * HH, 2), 256, 0, stream>>>(x, w, bias, sx, out);
  }
}